// Round 3
// baseline (5248.491 us; speedup 1.0000x reference)
//
#include <hip/hip_runtime.h>
#include <math.h>

namespace {

constexpr int T_ = 8, B_ = 32, D_ = 768, M_ = 8, S_ = 2, L_ = 2, H_ = 8;
constexpr int d_ = D_ / S_;   // 384
constexpr int P_ = M_ * S_;   // 16
constexpr int HD = D_ / H_;   // 96
constexpr float EPSF = 1e-5f;
constexpr int KNOFOLD = 1 << 30;

__device__ __forceinline__ float wredS(float v) {
#pragma unroll
  for (int o = 32; o; o >>= 1) v += __shfl_xor(v, o);
  return v;
}
__device__ __forceinline__ float wredM(float v) {
#pragma unroll
  for (int o = 32; o; o >>= 1) v = fmaxf(v, __shfl_xor(v, o));
  return v;
}
__device__ __forceinline__ float blockSum(float v, float* red, int nw) {
  v = wredS(v);
  if ((threadIdx.x & 63) == 0) red[threadIdx.x >> 6] = v;
  __syncthreads();
  float r = 0.f;
  for (int i = 0; i < nw; ++i) r += red[i];
  __syncthreads();
  return r;
}
__device__ __forceinline__ float blockMax(float v, float* red, int nw) {
  v = wredM(v);
  if ((threadIdx.x & 63) == 0) red[threadIdx.x >> 6] = v;
  __syncthreads();
  float r = red[0];
  for (int i = 1; i < nw; ++i) r = fmaxf(r, red[i]);
  __syncthreads();
  return r;
}
__device__ __forceinline__ float sigm(float x) { return 1.f / (1.f + expf(-x)); }

// Shared 32x128-tile GEMM body. C tile at (r0, n0). 256 threads.
// TRANSB=true : W is (N,K) row-major (C = A @ W^T), W row stride = K
// TRANSB=false: W is (K,N) row-major (C = A @ W),   W row stride = N
// A k-fold: for k0 >= kfold, A base += kfoldOff and k index -= kfold
// (lets a row of A be the concat of two strided slices; tiles must not straddle).
// EPI: 0 = bias, 1 = bias+relu, 2 = (bias)*scale
template <bool TRANSB, int EPI>
__device__ __forceinline__ void gemm_body(
    const float* __restrict__ Ab, int lda, const float* __restrict__ Wb,
    const float* __restrict__ biasz, float* __restrict__ Cb, int r0, int n0,
    int N, int K, float scale, int kfold, int kfoldOff) {
  __shared__ float As[32][36];   // [k][r]
  __shared__ float Bs[32][132];  // [k][n]
  const int tid = threadIdx.x;
  const int rg = tid >> 4, cg = tid & 15;
  float acc[2][8];
#pragma unroll
  for (int i = 0; i < 2; ++i)
#pragma unroll
    for (int j = 0; j < 8; ++j) acc[i][j] = 0.f;
  for (int k0 = 0; k0 < K; k0 += 32) {
    const float* Ak = Ab + (k0 >= kfold ? kfoldOff : 0);
    const int k0e = k0 - (k0 >= kfold ? kfold : 0);
    {
      const int r = tid >> 3, kq = (tid & 7) << 2;
      const float4 v = *(const float4*)(Ak + (size_t)(r0 + r) * lda + k0e + kq);
      As[kq + 0][r] = v.x; As[kq + 1][r] = v.y;
      As[kq + 2][r] = v.z; As[kq + 3][r] = v.w;
    }
#pragma unroll
    for (int i = 0; i < 4; ++i) {
      const int li = tid + i * 256;
      if (TRANSB) {
        const int n = li >> 3, kq = (li & 7) << 2;
        const float4 v = *(const float4*)(Wb + (size_t)(n0 + n) * K + k0 + kq);
        Bs[kq + 0][n] = v.x; Bs[kq + 1][n] = v.y;
        Bs[kq + 2][n] = v.z; Bs[kq + 3][n] = v.w;
      } else {
        const int k = li >> 5, nq = (li & 31) << 2;
        const float4 v = *(const float4*)(Wb + (size_t)(k0 + k) * N + n0 + nq);
        *(float4*)&Bs[k][nq] = v;
      }
    }
    __syncthreads();
#pragma unroll
    for (int kk = 0; kk < 32; ++kk) {
      const float2 a = *(const float2*)&As[kk][rg * 2];
      const float4 b0 = *(const float4*)&Bs[kk][cg * 4];
      const float4 b1 = *(const float4*)&Bs[kk][cg * 4 + 64];
      acc[0][0] += a.x * b0.x; acc[0][1] += a.x * b0.y;
      acc[0][2] += a.x * b0.z; acc[0][3] += a.x * b0.w;
      acc[0][4] += a.x * b1.x; acc[0][5] += a.x * b1.y;
      acc[0][6] += a.x * b1.z; acc[0][7] += a.x * b1.w;
      acc[1][0] += a.y * b0.x; acc[1][1] += a.y * b0.y;
      acc[1][2] += a.y * b0.z; acc[1][3] += a.y * b0.w;
      acc[1][4] += a.y * b1.x; acc[1][5] += a.y * b1.y;
      acc[1][6] += a.y * b1.z; acc[1][7] += a.y * b1.w;
    }
    __syncthreads();
  }
  float bv[8] = {0.f, 0.f, 0.f, 0.f, 0.f, 0.f, 0.f, 0.f};
  if (biasz) {
    const float* bb = biasz + n0 + cg * 4;
#pragma unroll
    for (int j = 0; j < 4; ++j) { bv[j] = bb[j]; bv[4 + j] = bb[64 + j]; }
  }
#pragma unroll
  for (int i = 0; i < 2; ++i) {
#pragma unroll
    for (int half = 0; half < 2; ++half) {
      float4 o;
      o.x = acc[i][half * 4 + 0] + bv[half * 4 + 0];
      o.y = acc[i][half * 4 + 1] + bv[half * 4 + 1];
      o.z = acc[i][half * 4 + 2] + bv[half * 4 + 2];
      o.w = acc[i][half * 4 + 3] + bv[half * 4 + 3];
      if (EPI == 1) {
        o.x = fmaxf(o.x, 0.f); o.y = fmaxf(o.y, 0.f);
        o.z = fmaxf(o.z, 0.f); o.w = fmaxf(o.w, 0.f);
      }
      if (EPI == 2) { o.x *= scale; o.y *= scale; o.z *= scale; o.w *= scale; }
      *(float4*)(Cb + (size_t)(r0 + rg * 2 + i) * N + n0 + half * 64 + cg * 4) = o;
    }
  }
}

// Batched GEMM. A_z base = A + (z>>1)*sAhi + (z&1)*sAlo (normal stride c: pass 2c, c;
// shared A: 0,0; z-linear c*z: pass 2c, c with base offset folded into A).
template <bool TRANSB, int EPI>
__global__ __launch_bounds__(256) void k_gemm(
    const float* __restrict__ A, int sAhi, int sAlo, int lda,
    const float* __restrict__ W, int sW, const float* __restrict__ bias, int sB,
    float* __restrict__ C, int sC, int N, int K, float scale, int kfold,
    int kfoldOff) {
  const int z = blockIdx.z;
  const float* Ab = A + (size_t)(z >> 1) * sAhi + (size_t)(z & 1) * sAlo;
  const float* Wb = W + (size_t)z * sW;
  const float* biasz = bias ? bias + (size_t)z * sB : nullptr;
  float* Cb = C + (size_t)z * sC;
  gemm_body<TRANSB, EPI>(Ab, lda, Wb, biasz, Cb, blockIdx.y * 32,
                         blockIdx.x * 128, N, K, scale, kfold, kfoldOff);
}

// Two independent 32x384x384 GEMM batches (rec: z<16, act: z>=16) in one dispatch.
__global__ __launch_bounds__(256) void k_recact(
    const float* __restrict__ A0, int hi0, int lo0, int lda0,
    const float* __restrict__ W0,
    const float* __restrict__ A1, int hi1, int lo1, int lda1,
    const float* __restrict__ W1, int sW, float* __restrict__ C0,
    float* __restrict__ C1) {
  const int z = blockIdx.z;
  const int which = z >> 4, zz = z & 15;
  const float* Ab = which ? A1 + (size_t)(zz >> 1) * hi1 + (size_t)(zz & 1) * lo1
                          : A0 + (size_t)(zz >> 1) * hi0 + (size_t)(zz & 1) * lo0;
  const int lda = which ? lda1 : lda0;
  const float* Wb = (which ? W1 : W0) + (size_t)zz * sW;
  float* Cb = (which ? C1 : C0) + (size_t)zz * (B_ * d_);
  gemm_body<false, 0>(Ab, lda, Wb, nullptr, Cb, 0, blockIdx.x * 128, d_, d_,
                      1.f, KNOFOLD, 0);
}

// Attention core: one wave per (m,b). q pre-scaled. kv: (m, s*32+b, 1536),
// cols 0..767 = k, 768..1535 = v.
__global__ __launch_bounds__(64) void k_attn(const float* __restrict__ qb,
    const float* __restrict__ kvb, float* __restrict__ ob) {
  __shared__ float as_[8][8];
  const int mb = blockIdx.x, m = mb >> 5, b = mb & 31;
  const int t = threadIdx.x, h = t >> 3, s = t & 7;
  const float* qrow = qb + (size_t)mb * D_ + h * HD;
  const float* krow = kvb + ((size_t)m * 256 + s * 32 + b) * (2 * D_) + h * HD;
  float sc = 0.f;
#pragma unroll 8
  for (int e = 0; e < HD; ++e) sc += qrow[e] * krow[e];
  float mx = sc;
#pragma unroll
  for (int o = 1; o < 8; o <<= 1) mx = fmaxf(mx, __shfl_xor(mx, o));
  const float ex = expf(sc - mx);
  float sm = ex;
#pragma unroll
  for (int o = 1; o < 8; o <<= 1) sm += __shfl_xor(sm, o);
  as_[h][s] = ex / sm;
  __syncthreads();
  const float* vbase = kvb + (size_t)m * 256 * (2 * D_) + D_;
  for (int e = t; e < D_; e += 64) {
    const int hh = e / HD;
    float o = 0.f;
#pragma unroll
    for (int ss = 0; ss < 8; ++ss)
      o += as_[hh][ss] * vbase[(size_t)(ss * 32 + b) * (2 * D_) + e];
    ob[(size_t)mb * D_ + e] = o;
  }
}

// pred-net nonlinearity: nt (P,B,3d) -> dp,sr,gb updated in place, mod (P,B,d), sd (P,d)
__global__ __launch_bounds__(384) void k_mod(const float* __restrict__ nt,
    float* __restrict__ dp, float* __restrict__ sr, float* __restrict__ gb,
    float* __restrict__ mod, float* __restrict__ sd,
    const float* __restrict__ alpha, const float* __restrict__ decay, int l) {
  const int p = blockIdx.x, j = threadIdx.x;
  const int pl = p * L_ + l;
  const float al = alpha[(size_t)pl * d_ + j];
  const float dc = decay[(size_t)pl * d_ + j];
  const size_t sbase = (size_t)pl * B_ * d_;
  float gsum = 0.f;
  for (int b = 0; b < B_; ++b) {
    const float* row = nt + ((size_t)p * B_ + b) * (3 * d_) + 3 * j;
    const float pd = row[0], ps = row[1], pg = row[2];
    const float inv = 1.f / fmaxf(ps, 1e-6f);
    const size_t ix = sbase + (size_t)b * d_ + j;
    const float dpv = tanhf(dp[ix] + pd * inv);
    const float srv = sigm(sr[ix] + ps);
    const float gbv = sigm(gb[ix] + pg * inv);
    dp[ix] = dpv; sr[ix] = srv; gb[ix] = gbv;
    mod[((size_t)p * B_ + b) * d_ + j] = al * dpv * srv;
    gsum += gbv;
  }
  sd[(size_t)p * d_ + j] = dc * sigm(gsum * (1.f / B_));
}

// Plastic weight update with INLINE activation row-softmax stats.
// W_new = W*(1-sd[i]) + softmax_row(W) * (softmax_row(act)^T @ mod)/B
// which=0 -> (Wst, pa); which=1 -> (Wrst, pr). 8 W-rows per block.
__global__ __launch_bounds__(256) void k_wsm(float* __restrict__ Wst,
    float* __restrict__ Wrst, const float* __restrict__ pa,
    const float* __restrict__ pr, const float* __restrict__ mod,
    const float* __restrict__ sd, int l) {
  __shared__ float mods[B_][d_];   // 48 KB
  __shared__ float asms[8][B_];
  __shared__ float rm_s[B_], rs_s[B_];
  __shared__ float red[4];
  const int i0 = blockIdx.x * 8, p = blockIdx.y, which = blockIdx.z;
  const int tid = threadIdx.x;
  const int pl = p * L_ + l;
  float* W = (which ? Wrst : Wst) + (size_t)pl * d_ * d_;
  const float* act = (which ? pr : pa) + (size_t)pl * B_ * d_;
  for (int ix = tid; ix < B_ * d_; ix += 256)
    mods[ix / d_][ix % d_] = mod[(size_t)p * B_ * d_ + ix];
  {  // inline row stats: 8 lanes per activation row
    const int bb = tid >> 3, l8 = tid & 7;
    const float* ar = act + (size_t)bb * d_;
    float mx = -3.4e38f;
    for (int j = l8; j < d_; j += 8) mx = fmaxf(mx, ar[j]);
#pragma unroll
    for (int o = 1; o < 8; o <<= 1) mx = fmaxf(mx, __shfl_xor(mx, o));
    float s = 0.f;
    for (int j = l8; j < d_; j += 8) s += expf(ar[j] - mx);
#pragma unroll
    for (int o = 1; o < 8; o <<= 1) s += __shfl_xor(s, o);
    if (l8 == 0) { rm_s[bb] = mx; rs_s[bb] = s; }
  }
  __syncthreads();
  {
    const int ii = tid >> 5, b = tid & 31;
    asms[ii][b] = expf(act[(size_t)b * d_ + i0 + ii] - rm_s[b]) / rs_s[b];
  }
  __syncthreads();
  for (int ii = 0; ii < 8; ++ii) {
    const int i = i0 + ii;
    float* Wrow = W + (size_t)i * d_;
    const float w1v = Wrow[tid];
    const bool a2 = tid < (d_ - 256);
    const float w2v = a2 ? Wrow[tid + 256] : 0.f;
    const float mx = blockMax(a2 ? fmaxf(w1v, w2v) : w1v, red, 4);
    const float e1 = expf(w1v - mx);
    const float e2 = a2 ? expf(w2v - mx) : 0.f;
    const float ssum = blockSum(e1 + e2, red, 4);
    const float sdi = sd[(size_t)p * d_ + i];
    float o1 = 0.f, o2 = 0.f;
    const float* am = asms[ii];
#pragma unroll 8
    for (int b = 0; b < B_; ++b) {
      const float a = am[b];
      o1 += a * mods[b][tid];
      if (a2) o2 += a * mods[b][tid + 256];
    }
    Wrow[tid] = w1v * (1.f - sdi) + (e1 / ssum) * (o1 * (1.f / B_));
    if (a2) Wrow[tid + 256] = w2v * (1.f - sdi) + (e2 / ssum) * (o2 * (1.f / B_));
    __syncthreads();
  }
}

// Fused: pr = LN(rec_pre)*lrg+lrb ; pa = LN(relu(act_pre + pr))*lag+lab.
// One block per (p,b), 128 threads, 3 elems/thread.
__global__ __launch_bounds__(128) void k_lnpair(const float* __restrict__ gr,
    const float* __restrict__ ga, float* __restrict__ prs,
    float* __restrict__ pas, const float* __restrict__ lrg,
    const float* __restrict__ lrb, const float* __restrict__ lag,
    const float* __restrict__ lab, int l) {
  __shared__ float red[2];
  const int pb = blockIdx.x, p = pb >> 5, b = pb & 31;
  const int pl = p * L_ + l;
  const int t = threadIdx.x;
  const size_t soff = ((size_t)pl * B_ + b) * d_;
  const float* xr = gr + (size_t)pb * d_;
  float v0 = xr[t], v1 = xr[t + 128], v2 = xr[t + 256];
  float mu = blockSum(v0 + v1 + v2, red, 2) * (1.f / d_);
  float e0 = v0 - mu, e1 = v1 - mu, e2 = v2 - mu;
  float va = blockSum(e0 * e0 + e1 * e1 + e2 * e2, red, 2) * (1.f / d_);
  float inv = 1.f / sqrtf(va + EPSF);
  const float* G = lrg + (size_t)pl * d_;
  const float* Bv = lrb + (size_t)pl * d_;
  const float r0v = e0 * inv * G[t] + Bv[t];
  const float r1v = e1 * inv * G[t + 128] + Bv[t + 128];
  const float r2v = e2 * inv * G[t + 256] + Bv[t + 256];
  prs[soff + t] = r0v;
  prs[soff + t + 128] = r1v;
  prs[soff + t + 256] = r2v;
  const float* xa = ga + (size_t)pb * d_;
  float a0 = fmaxf(xa[t] + r0v, 0.f);
  float a1 = fmaxf(xa[t + 128] + r1v, 0.f);
  float a2 = fmaxf(xa[t + 256] + r2v, 0.f);
  mu = blockSum(a0 + a1 + a2, red, 2) * (1.f / d_);
  e0 = a0 - mu; e1 = a1 - mu; e2 = a2 - mu;
  va = blockSum(e0 * e0 + e1 * e1 + e2 * e2, red, 2) * (1.f / d_);
  inv = 1.f / sqrtf(va + EPSF);
  const float* G2 = lag + (size_t)pl * d_;
  const float* B2 = lab + (size_t)pl * d_;
  pas[soff + t] = e0 * inv * G2[t] + B2[t];
  pas[soff + t + 128] = e1 * inv * G2[t + 128] + B2[t + 128];
  pas[soff + t + 256] = e2 * inv * G2[t + 256] + B2[t + 256];
}

// Output LN over D, writes next-step mem.
__global__ __launch_bounds__(256) void k_lnout(const float* __restrict__ pre,
    float* __restrict__ memo, const float* __restrict__ gg,
    const float* __restrict__ bb) {
  __shared__ float red[4];
  const int mb = blockIdx.x, m = mb >> 5;
  const float* x = pre + (size_t)mb * D_;
  const int t = threadIdx.x;
  const float v0 = x[t], v1 = x[t + 256], v2 = x[t + 512];
  const float mu = blockSum(v0 + v1 + v2, red, 4) * (1.f / D_);
  const float e0 = v0 - mu, e1 = v1 - mu, e2 = v2 - mu;
  const float va = blockSum(e0 * e0 + e1 * e1 + e2 * e2, red, 4) * (1.f / D_);
  const float inv = 1.f / sqrtf(va + EPSF);
  const float* G = gg + (size_t)m * D_;
  const float* Bv = bb + (size_t)m * D_;
  float* o = memo + (size_t)mb * D_;
  o[t] = e0 * inv * G[t] + Bv[t];
  o[t + 256] = e1 * inv * G[t + 256] + Bv[t + 256];
  o[t + 512] = e2 * inv * G[t + 512] + Bv[t + 512];
}

}  // namespace

extern "C" void kernel_launch(void* const* d_in, const int* in_sizes, int n_in,
                              void* d_out, int out_size, void* d_ws, size_t ws_size,
                              hipStream_t stream) {
  const float* x     = (const float*)d_in[0];
  const float* mem0  = (const float*)d_in[1];
  const float* ainw  = (const float*)d_in[2];
  const float* ainb  = (const float*)d_in[3];
  const float* aoutw = (const float*)d_in[4];
  const float* aoutb = (const float*)d_in[5];
  const float* hebw  = (const float*)d_in[6];
  const float* hebrw = (const float*)d_in[7];
  const float* alpha = (const float*)d_in[8];
  const float* decay = (const float*)d_in[9];
  const float* lag   = (const float*)d_in[10];
  const float* lab   = (const float*)d_in[11];
  const float* lrg   = (const float*)d_in[12];
  const float* lrb   = (const float*)d_in[13];
  const float* pw1   = (const float*)d_in[14];
  const float* pb1   = (const float*)d_in[15];
  const float* pw2   = (const float*)d_in[16];
  const float* pb2   = (const float*)d_in[17];
  const float* outw  = (const float*)d_in[18];
  const float* outb  = (const float*)d_in[19];
  const float* lng   = (const float*)d_in[20];
  const float* lnb   = (const float*)d_in[21];

  float* w = (float*)d_ws;
  size_t off = 0;
  auto alloc = [&](size_t n) { float* p = w + off; off += n; return p; };
  float* mem   = alloc((size_t)M_ * B_ * D_);
  float* qb    = alloc((size_t)M_ * B_ * D_);
  float* kvb   = alloc((size_t)M_ * M_ * B_ * 2 * D_);
  float* ob    = alloc((size_t)M_ * B_ * D_);
  float* attnh = alloc((size_t)M_ * B_ * D_);
  float* t1    = alloc((size_t)P_ * B_ * d_);
  float* nt    = alloc((size_t)P_ * B_ * 3 * d_);
  float* modb  = alloc((size_t)P_ * B_ * d_);
  float* sdb   = alloc((size_t)P_ * d_);
  float* gtmp  = alloc((size_t)2 * P_ * B_ * d_);   // [0]=rec_pre, [1]=act_pre
  float* otmp  = alloc((size_t)M_ * B_ * D_);
  float* pa    = alloc((size_t)P_ * L_ * B_ * d_);  // pa,pr,dp,sr,gb contiguous
  float* pr    = alloc((size_t)P_ * L_ * B_ * d_);
  float* dp    = alloc((size_t)P_ * L_ * B_ * d_);
  float* sr    = alloc((size_t)P_ * L_ * B_ * d_);
  float* gbst  = alloc((size_t)P_ * L_ * B_ * d_);
  float* Wst   = alloc((size_t)P_ * L_ * d_ * d_);
  float* Wrst  = alloc((size_t)P_ * L_ * d_ * d_);
  float* gtmp0 = gtmp;
  float* gtmp1 = gtmp + (size_t)P_ * B_ * d_;
  (void)in_sizes; (void)n_in; (void)out_size; (void)ws_size;

  // Recurrent-state init (workspace is re-poisoned before every timed call).
  hipMemcpyAsync(mem, mem0, sizeof(float) * M_ * B_ * D_, hipMemcpyDeviceToDevice, stream);
  hipMemcpyAsync(Wst, hebw, sizeof(float) * P_ * L_ * d_ * d_, hipMemcpyDeviceToDevice, stream);
  hipMemcpyAsync(Wrst, hebrw, sizeof(float) * P_ * L_ * d_ * d_, hipMemcpyDeviceToDevice, stream);
  hipMemsetAsync(pa, 0, sizeof(float) * 5 * P_ * L_ * B_ * d_, stream);

  const float qscale = 1.0f / sqrtf((float)HD);
  const int LBd = L_ * B_ * d_;
  const int Bd = B_ * d_;

  auto gemm = [&](bool transB, int epi, const float* A, int sAhi, int sAlo,
                  int lda, const float* Wp, int sW, const float* bias, int sB,
                  float* C, int sC, int R, int N, int K, int G, float scale,
                  int kfold, int kfoldOff) {
    dim3 grid(N / 128, R / 32, G), blk(256);
    if (transB && epi == 0)
      k_gemm<true, 0><<<grid, blk, 0, stream>>>(A, sAhi, sAlo, lda, Wp, sW, bias, sB, C, sC, N, K, scale, kfold, kfoldOff);
    else if (transB && epi == 2)
      k_gemm<true, 2><<<grid, blk, 0, stream>>>(A, sAhi, sAlo, lda, Wp, sW, bias, sB, C, sC, N, K, scale, kfold, kfoldOff);
    else if (!transB && epi == 0)
      k_gemm<false, 0><<<grid, blk, 0, stream>>>(A, sAhi, sAlo, lda, Wp, sW, bias, sB, C, sC, N, K, scale, kfold, kfoldOff);
    else
      k_gemm<false, 1><<<grid, blk, 0, stream>>>(A, sAhi, sAlo, lda, Wp, sW, bias, sB, C, sC, N, K, scale, kfold, kfoldOff);
  };

  for (int t = 0; t < T_; ++t) {
    const float* xt = x + (size_t)t * B_ * D_;
    // q = (x_t @ wq^T + bq) * hd^-0.5  -> qb (M,B,D)
    gemm(true, 2, xt, 0, 0, D_, ainw, 3 * D_ * D_, ainb, 3 * D_, qb, B_ * D_,
         B_, D_, D_, M_, qscale, KNOFOLD, 0);
    // kv = mem_flat @ [wk;wv]^T + b   -> kvb (M, 256, 1536)
    gemm(true, 0, mem, 0, 0, D_, ainw + D_ * D_, 3 * D_ * D_, ainb + D_, 3 * D_,
         kvb, M_ * B_ * 2 * D_, M_ * B_, 2 * D_, D_, M_, 1.f, KNOFOLD, 0);
    k_attn<<<dim3(M_ * B_), dim3(64), 0, stream>>>(qb, kvb, ob);
    // attn out-proj -> attnh (M,B,D)
    gemm(true, 0, ob, 2 * B_ * D_, B_ * D_, D_, aoutw, D_ * D_, aoutb, D_,
         attnh, B_ * D_, B_, D_, D_, M_, 1.f, KNOFOLD, 0);

    for (int l = 0; l < L_; ++l) {
      // t1 = relu(pa[:,l] @ w1 + b1)
      gemm(false, 1, pa + (size_t)l * Bd, 2 * LBd, LBd, d_,
           pw1 + (size_t)l * d_ * d_, L_ * d_ * d_, pb1 + l * d_, L_ * d_,
           t1, Bd, B_, d_, d_, P_, 1.f, KNOFOLD, 0);
      // nt = t1 @ w2 + b2
      gemm(false, 0, t1, 2 * Bd, Bd, d_, pw2 + (size_t)l * d_ * 3 * d_,
           L_ * d_ * 3 * d_, pb2 + l * 3 * d_, L_ * 3 * d_, nt, 3 * Bd,
           B_, 3 * d_, d_, P_, 1.f, KNOFOLD, 0);
      k_mod<<<dim3(P_), dim3(d_), 0, stream>>>(nt, dp, sr, gbst, modb, sdb,
                                               alpha, decay, l);
      k_wsm<<<dim3(d_ / 8, P_, 2), dim3(256), 0, stream>>>(Wst, Wrst, pa, pr,
                                                           modb, sdb, l);
      // rec_pre = pa[:,l] @ Wr_new ; act_pre = xin @ W_new  (one dispatch)
      if (l == 0)
        k_recact<<<dim3(3, 1, 32), dim3(256), 0, stream>>>(
            pa + (size_t)l * Bd, 2 * LBd, LBd, d_, Wrst + (size_t)l * d_ * d_,
            attnh, B_ * D_, d_, D_, Wst + (size_t)l * d_ * d_,
            L_ * d_ * d_, gtmp0, gtmp1);
      else
        k_recact<<<dim3(3, 1, 32), dim3(256), 0, stream>>>(
            pa + (size_t)l * Bd, 2 * LBd, LBd, d_, Wrst + (size_t)l * d_ * d_,
            pa, 2 * LBd, LBd, d_, Wst + (size_t)l * d_ * d_,
            L_ * d_ * d_, gtmp0, gtmp1);
      k_lnpair<<<dim3(P_ * B_), dim3(128), 0, stream>>>(gtmp0, gtmp1, pr, pa,
                                                        lrg, lrb, lag, lab, l);
    }

    // out = LN(cat @ out_w^T + out_b); cat read directly from pa[:,1] via k-fold:
    // row(m,b), k<384 -> pa[(2m)*L+1][b][k]; k>=384 -> pa[(2m+1)*L+1][b][k-384]
    gemm(true, 0, pa + Bd, 8 * Bd, 4 * Bd, d_, outw, D_ * D_, outb, D_,
         otmp, B_ * D_, B_, D_, D_, M_, 1.f, d_, 2 * Bd);
    k_lnout<<<dim3(M_ * B_), dim3(256), 0, stream>>>(otmp, mem, lng, lnb);
  }

  hipMemcpyAsync(d_out, mem, sizeof(float) * M_ * B_ * D_, hipMemcpyDeviceToDevice, stream);
}